// Round 8
// baseline (77.734 us; speedup 1.0000x reference)
//
#include <hip/hip_runtime.h>
#include <hip/hip_fp16.h>

typedef unsigned int u32;
typedef unsigned short u16;
typedef __attribute__((ext_vector_type(8))) _Float16 f16x8;
typedef __attribute__((ext_vector_type(4))) float f32x4;
typedef __attribute__((ext_vector_type(4))) u32 u32x4;

#define K_DIM 4096
#define N_DIM 14336
#define BM 64
#define BN 128
#define BK 128            // = GROUP_SIZE: one scale group per iteration
#define NITER (K_DIM / BK)   // 16
#define NBLK 448          // (256/64) * (14336/128)
#define LDA 136           // halfwords per A-row (272 B)

union U4F8 { u32x4 u; f16x8 v; };

// dequant one int32 (8 nibbles, k-order [0,4,1,5,2,6,3,7]) -> f16x8 fragment
// w = RN( RN(s*q) - z ): fma(s, 1024+q, -1024s) single-rounds to RN(s*q)
// because d2 = -1024*s is EXACT in f16 (exponent shift). Bit-identical to ref.
__device__ __forceinline__ f16x8 dq8(u32 q, __half2 s2, __half2 d2, __half2 z2) {
  const u32 q1 = q >> 4, q2 = q >> 8, q3 = q >> 12;
  U4F8 r;
  const u32 x0 = ( q & 0x000F000Fu) | 0x64006400u;   // {1024+n_j, 1024+n_{j+4}}
  const u32 x1 = (q1 & 0x000F000Fu) | 0x64006400u;
  const u32 x2 = (q2 & 0x000F000Fu) | 0x64006400u;
  const u32 x3 = (q3 & 0x000F000Fu) | 0x64006400u;
  r.u.x = __builtin_bit_cast(u32, __hsub2(__hfma2(__builtin_bit_cast(__half2, x0), s2, d2), z2));
  r.u.y = __builtin_bit_cast(u32, __hsub2(__hfma2(__builtin_bit_cast(__half2, x1), s2, d2), z2));
  r.u.z = __builtin_bit_cast(u32, __hsub2(__hfma2(__builtin_bit_cast(__half2, x2), s2, d2), z2));
  r.u.w = __builtin_bit_cast(u32, __hsub2(__hfma2(__builtin_bit_cast(__half2, x3), s2, d2), z2));
  return r.v;
}

__device__ __forceinline__ u32 pkrtz(float a, float b) {  // exact: x was f16
  return __builtin_bit_cast(u32, __builtin_amdgcn_cvt_pkrtz(a, b));
}

__global__ __launch_bounds__(512, 4) void kivi_gemm(
    const float* __restrict__ X,    // x upconverted to f32 [256][4096]
    const int* __restrict__ QW,     // [512][14336]; nibble j of row r -> k = r*8+j
    const float* __restrict__ S,    // [32][14336]
    const float* __restrict__ Z,    // [32][14336]
    float* __restrict__ O)          // out f32 [256][14336]
{
  __shared__ __align__(16) u16 As[2][BM][LDA];   // 34,816 B (A only; B never in LDS)

  const int tid  = threadIdx.x;
  const int lane = tid & 63;
  const int w    = tid >> 6;

  // XCD-aware bijective swizzle: 448 = 8*56; m-minor so same-XCD shares QW panel
  const int b  = blockIdx.x;
  const int L  = (b & 7) * 56 + (b >> 3);
  const int m0 = (L & 3) * BM;
  const int n0 = (L >> 2) * BN;

  // 8 waves tile 64x128 as 2m x 4n wave-tiles of 32x32; frags 2m x 2n x 4ks
  const int wm = w >> 2, wn = w & 3;
  const int mb = wm * 32, nb = wn * 32;
  const int fr = lane & 15, fq = lane >> 4;
  const int cb = n0 + nb + fr;            // B col for ni=0 (ni=1 -> +16)

  // A staging: thread -> row tid>>3, 16 f32 at k-chunk (tid&7)*16
  const int arow = tid >> 3;
  const int acol = (tid & 7) * 16;

  f32x4 acc[2][2];
#pragma unroll
  for (int mi = 0; mi < 2; ++mi)
#pragma unroll
    for (int ni = 0; ni < 2; ++ni)
      acc[mi][ni] = (f32x4){0.f, 0.f, 0.f, 0.f};

  f32x4 aReg[4];
  u32 qC[4][2], qN[4][2];
  float svC[2], zvC[2], svN[2], zvN[2];

  auto loadAx = [&](int t) {
    const float* p = X + (size_t)(m0 + arow) * K_DIM + t * BK + acol;
    aReg[0] = *(const f32x4*)(p);
    aReg[1] = *(const f32x4*)(p + 4);
    aReg[2] = *(const f32x4*)(p + 8);
    aReg[3] = *(const f32x4*)(p + 12);
  };
  // sigma-pack pairs (j, j+4) to match dq8 k-order, two b128 writes
  auto writeAx = [&](int buf) {
#pragma unroll
    for (int c = 0; c < 2; ++c) {
      u32x4 pk;
      pk.x = pkrtz(aReg[c * 2][0], aReg[c * 2 + 1][0]);
      pk.y = pkrtz(aReg[c * 2][1], aReg[c * 2 + 1][1]);
      pk.z = pkrtz(aReg[c * 2][2], aReg[c * 2 + 1][2]);
      pk.w = pkrtz(aReg[c * 2][3], aReg[c * 2 + 1][3]);
      *(u32x4*)&As[buf][arow][acol + c * 8] = pk;
    }
  };
  auto loadBq = [&](int t, u32 (&q)[4][2], float (&s)[2], float (&z)[2]) {
    const size_t rbase = (size_t)(t * 16 + fq) * N_DIM + cb;   // q-row = k/8
#pragma unroll
    for (int ks = 0; ks < 4; ++ks)
#pragma unroll
      for (int ni = 0; ni < 2; ++ni)
        q[ks][ni] = *(const u32*)(QW + rbase + (size_t)ks * 4 * N_DIM + ni * 16);
#pragma unroll
    for (int ni = 0; ni < 2; ++ni) {
      s[ni] = S[(size_t)t * N_DIM + cb + ni * 16];   // group == K-tile (BK=128)
      z[ni] = Z[(size_t)t * N_DIM + cb + ni * 16];
    }
  };

  // prologue: stage tile 0
  loadAx(0);
  loadBq(0, qC, svC, zvC);
  writeAx(0);
  __syncthreads();

  const __half hneg1024 = __float2half(-1024.f);

  for (int i = 0; i < NITER; ++i) {
    const int cur = i & 1;
    const bool pf = (i + 1 < NITER);

    if (pf) {                       // issue ALL next-tile globals at iter top
      loadAx(i + 1);
      loadBq(i + 1, qN, svN, zvN);
    }

    // per-group dequant constants (group == K-tile i)
    __half2 s2[2], d2[2], z2[2];
#pragma unroll
    for (int ni = 0; ni < 2; ++ni) {
      const __half sh = __float2half(svC[ni]);     // matches ref astype(f16)
      const __half zh = __float2half(zvC[ni]);
      const __half dh = __hmul(sh, hneg1024);      // exact: exponent shift
      s2[ni] = __halves2half2(sh, sh);
      d2[ni] = __halves2half2(dh, dh);
      z2[ni] = __halves2half2(zh, zh);
    }

#pragma unroll
    for (int ks = 0; ks < 4; ++ks) {
      f16x8 af[2], bf[2];
#pragma unroll
      for (int mi = 0; mi < 2; ++mi)
        af[mi] = *(const f16x8*)&As[cur][mb + mi * 16 + fr][ks * 32 + fq * 8];
#pragma unroll
      for (int ni = 0; ni < 2; ++ni)
        bf[ni] = dq8(qC[ks][ni], s2[ni], d2[ni], z2[ni]);
#pragma unroll
      for (int mi = 0; mi < 2; ++mi)
#pragma unroll
        for (int ni = 0; ni < 2; ++ni)
          acc[mi][ni] = __builtin_amdgcn_mfma_f32_16x16x32_f16(
              af[mi], bf[ni], acc[mi][ni], 0, 0, 0);
    }

    if (pf) {
      writeAx(cur ^ 1);             // waits only on this iter's A loads
#pragma unroll
      for (int ks = 0; ks < 4; ++ks)
#pragma unroll
        for (int ni = 0; ni < 2; ++ni)
          qC[ks][ni] = qN[ks][ni];
#pragma unroll
      for (int ni = 0; ni < 2; ++ni) {
        svC[ni] = svN[ni]; zvC[ni] = zvN[ni];
      }
    }
    __syncthreads();
  }

  // epilogue: direct store, C/D layout col=lane&15, row=(lane>>4)*4+r
#pragma unroll
  for (int mi = 0; mi < 2; ++mi)
#pragma unroll
    for (int ni = 0; ni < 2; ++ni)
#pragma unroll
      for (int r = 0; r < 4; ++r) {
        const int row = m0 + mb + mi * 16 + fq * 4 + r;
        const int col = n0 + nb + ni * 16 + fr;
        O[(size_t)row * N_DIM + col] = acc[mi][ni][r];
      }
}

extern "C" void kernel_launch(void* const* d_in, const int* in_sizes, int n_in,
                              void* d_out, int out_size, void* d_ws, size_t ws_size,
                              hipStream_t stream) {
  const float* X  = (const float*)d_in[0];
  const int*   QW = (const int*)d_in[1];
  const float* S  = (const float*)d_in[2];
  const float* Zp = (const float*)d_in[3];
  float* O = (float*)d_out;
  hipLaunchKernelGGL(kivi_gemm, dim3(NBLK), dim3(512), 0, stream, X, QW, S, Zp, O);
}

// Round 9
// 69.617 us; speedup vs baseline: 1.1166x; 1.1166x over previous
//
#include <hip/hip_runtime.h>
#include <hip/hip_fp16.h>

typedef unsigned int u32;
typedef unsigned short u16;
typedef __attribute__((ext_vector_type(8))) _Float16 f16x8;
typedef __attribute__((ext_vector_type(4))) float f32x4;
typedef __attribute__((ext_vector_type(4))) u32 u32x4;

#define M_DIM 256
#define K_DIM 4096
#define N_DIM 14336
#define BM 32
#define BN 128
#define BK 128            // = GROUP_SIZE: one scale group per iteration
#define NITER (K_DIM / BK)                  // 32
#define NBLK ((M_DIM / BM) * (N_DIM / BN))  // 8 * 112 = 896
#define LDA 136           // halfwords per A-row (272 B), bank-uniform

union U4F8 { u32x4 u; f16x8 v; };

// dequant one int32 (8 nibbles, k-order [0,4,1,5,2,6,3,7]) -> f16x8 fragment
// w = RN( RN(s*q) - z ): fma(s, 1024+q, -1024s) single-rounds to RN(s*q)
// because d2 = -1024*s is EXACT in f16 (exponent shift). Bit-identical to ref.
__device__ __forceinline__ f16x8 dq8(u32 q, __half2 s2, __half2 d2, __half2 z2) {
  const u32 q1 = q >> 4, q2 = q >> 8, q3 = q >> 12;
  U4F8 r;
  const u32 x0 = ( q & 0x000F000Fu) | 0x64006400u;   // {1024+n_j, 1024+n_{j+4}}
  const u32 x1 = (q1 & 0x000F000Fu) | 0x64006400u;
  const u32 x2 = (q2 & 0x000F000Fu) | 0x64006400u;
  const u32 x3 = (q3 & 0x000F000Fu) | 0x64006400u;
  r.u.x = __builtin_bit_cast(u32, __hsub2(__hfma2(__builtin_bit_cast(__half2, x0), s2, d2), z2));
  r.u.y = __builtin_bit_cast(u32, __hsub2(__hfma2(__builtin_bit_cast(__half2, x1), s2, d2), z2));
  r.u.z = __builtin_bit_cast(u32, __hsub2(__hfma2(__builtin_bit_cast(__half2, x2), s2, d2), z2));
  r.u.w = __builtin_bit_cast(u32, __hsub2(__hfma2(__builtin_bit_cast(__half2, x3), s2, d2), z2));
  return r.v;
}

__device__ __forceinline__ u32 pkrtz(float a, float b) {  // exact: x was f16
  return __builtin_bit_cast(u32, __builtin_amdgcn_cvt_pkrtz(a, b));
}

__global__ __launch_bounds__(256, 4) void kivi_gemm(
    const float* __restrict__ X,    // x upconverted to f32 [256][4096]
    const int* __restrict__ QW,     // [512][14336]; nibble j of row r -> k = r*8+j
    const float* __restrict__ S,    // [32][14336]
    const float* __restrict__ Z,    // [32][14336]
    float* __restrict__ O)          // out f32 [256][14336]
{
  __shared__ __align__(16) u16 As[2][BM][LDA];   // 17,408 B (A only; B stays in regs)

  const int tid  = threadIdx.x;
  const int lane = tid & 63;
  const int wn   = tid >> 6;        // 4 waves = 4 n-subtiles of 32 cols

  // XCD-aware bijective swizzle: 896 = 8*112; same-XCD gets 14 n-panels x 8 m-tiles
  const int b  = blockIdx.x;
  const int L  = (b & 7) * 112 + (b >> 3);
  const int m0 = (L & 7) * BM;
  const int n0 = (L >> 3) * BN;

  const int nb = wn * 32;
  const int fr = lane & 15, fq = lane >> 4;
  const int cb = n0 + nb + fr;      // B col for ni=0 (ni=1 -> +16)

  // A staging: thread -> row tid>>3 (0..31), 16 f32 at k-chunk (tid&7)*16
  const int arow = tid >> 3;
  const int acol = (tid & 7) * 16;

  f32x4 acc[2][2];
#pragma unroll
  for (int mi = 0; mi < 2; ++mi)
#pragma unroll
    for (int ni = 0; ni < 2; ++ni)
      acc[mi][ni] = (f32x4){0.f, 0.f, 0.f, 0.f};

  // two static register sets (ping-pong, no copies)
  f32x4 aR0[4], aR1[4];
  u32 qS0[4][2], qS1[4][2];
  float sv0[2], zv0[2], sv1[2], zv1[2];

  auto loadAx = [&](int t, f32x4 (&aReg)[4]) {
    const float* p = X + (size_t)(m0 + arow) * K_DIM + t * BK + acol;
    aReg[0] = *(const f32x4*)(p);
    aReg[1] = *(const f32x4*)(p + 4);
    aReg[2] = *(const f32x4*)(p + 8);
    aReg[3] = *(const f32x4*)(p + 12);
  };
  // sigma-pack pairs (j, j+4) to match dq8 k-order, two b128 writes
  auto writeAx = [&](int buf, f32x4 (&aReg)[4]) {
#pragma unroll
    for (int c = 0; c < 2; ++c) {
      u32x4 pk;
      pk.x = pkrtz(aReg[c * 2][0], aReg[c * 2 + 1][0]);
      pk.y = pkrtz(aReg[c * 2][1], aReg[c * 2 + 1][1]);
      pk.z = pkrtz(aReg[c * 2][2], aReg[c * 2 + 1][2]);
      pk.w = pkrtz(aReg[c * 2][3], aReg[c * 2 + 1][3]);
      *(u32x4*)&As[buf][arow][acol + c * 8] = pk;
    }
  };
  auto loadBq = [&](int t, u32 (&q)[4][2], float (&s)[2], float (&z)[2]) {
    const size_t rbase = (size_t)(t * 16 + fq) * N_DIM + cb;   // q-row = k/8
#pragma unroll
    for (int ks = 0; ks < 4; ++ks)
#pragma unroll
      for (int ni = 0; ni < 2; ++ni)
        q[ks][ni] = *(const u32*)(QW + rbase + (size_t)ks * 4 * N_DIM + ni * 16);
#pragma unroll
    for (int ni = 0; ni < 2; ++ni) {
      s[ni] = S[(size_t)t * N_DIM + cb + ni * 16];   // group == K-tile (BK=128)
      z[ni] = Z[(size_t)t * N_DIM + cb + ni * 16];
    }
  };
  auto computeT = [&](int buf, u32 (&q)[4][2], float (&s)[2], float (&z)[2]) {
    const __half hneg1024 = __float2half(-1024.f);
    __half2 s2[2], d2[2], z2[2];
#pragma unroll
    for (int ni = 0; ni < 2; ++ni) {
      const __half sh = __float2half(s[ni]);     // matches ref astype(f16)
      const __half zh = __float2half(z[ni]);
      const __half dh = __hmul(sh, hneg1024);    // exact: exponent shift
      s2[ni] = __halves2half2(sh, sh);
      d2[ni] = __halves2half2(dh, dh);
      z2[ni] = __halves2half2(zh, zh);
    }
#pragma unroll
    for (int ks = 0; ks < 4; ++ks) {
      f16x8 af[2], bf[2];
#pragma unroll
      for (int mi = 0; mi < 2; ++mi)
        af[mi] = *(const f16x8*)&As[buf][mi * 16 + fr][ks * 32 + fq * 8];
#pragma unroll
      for (int ni = 0; ni < 2; ++ni)
        bf[ni] = dq8(q[ks][ni], s2[ni], d2[ni], z2[ni]);
#pragma unroll
      for (int mi = 0; mi < 2; ++mi)
#pragma unroll
        for (int ni = 0; ni < 2; ++ni)
          acc[mi][ni] = __builtin_amdgcn_mfma_f32_16x16x32_f16(
              af[mi], bf[ni], acc[mi][ni], 0, 0, 0);
    }
  };

  // prologue: stage tile 0 into buf 0
  loadAx(0, aR0); loadBq(0, qS0, sv0, zv0);
  writeAx(0, aR0);
  __syncthreads();

#pragma unroll 1
  for (int i = 0; i < NITER; i += 2) {
    // even iter: compute buf0/set0, prefetch t=i+1 -> set1, write to buf1
    if (i + 1 < NITER) { loadAx(i + 1, aR1); loadBq(i + 1, qS1, sv1, zv1); }
    __builtin_amdgcn_sched_barrier(0);    // pin prefetch issue above compute
    computeT(0, qS0, sv0, zv0);
    if (i + 1 < NITER) writeAx(1, aR1);
    __syncthreads();

    // odd iter: compute buf1/set1, prefetch t=i+2 -> set0, write to buf0
    if (i + 1 < NITER) {
      if (i + 2 < NITER) { loadAx(i + 2, aR0); loadBq(i + 2, qS0, sv0, zv0); }
      __builtin_amdgcn_sched_barrier(0);
      computeT(1, qS1, sv1, zv1);
      if (i + 2 < NITER) writeAx(0, aR0);
      __syncthreads();
    }
  }

  // epilogue: direct store, C/D layout col=lane&15, row=(lane>>4)*4+r
#pragma unroll
  for (int mi = 0; mi < 2; ++mi)
#pragma unroll
    for (int ni = 0; ni < 2; ++ni)
#pragma unroll
      for (int r = 0; r < 4; ++r) {
        const int row = m0 + mi * 16 + fq * 4 + r;
        const int col = n0 + nb + ni * 16 + fr;
        O[(size_t)row * N_DIM + col] = acc[mi][ni][r];
      }
}

extern "C" void kernel_launch(void* const* d_in, const int* in_sizes, int n_in,
                              void* d_out, int out_size, void* d_ws, size_t ws_size,
                              hipStream_t stream) {
  const float* X  = (const float*)d_in[0];
  const int*   QW = (const int*)d_in[1];
  const float* S  = (const float*)d_in[2];
  const float* Zp = (const float*)d_in[3];
  float* O = (float*)d_out;
  hipLaunchKernelGGL(kivi_gemm, dim3(NBLK), dim3(256), 0, stream, X, QW, S, Zp, O);
}